// Round 3
// baseline (389.932 us; speedup 1.0000x reference)
//
#include <hip/hip_runtime.h>
#include <hip/hip_cooperative_groups.h>

namespace cg = cooperative_groups;

#define THREADS 256

// ---------------------------------------------------------------------------
// Block helpers (each leaves sdata reusable: trailing __syncthreads()).
// ---------------------------------------------------------------------------
__device__ __forceinline__ int blockReduceSum(int v, int* sdata) {
    int tid = threadIdx.x;
    sdata[tid] = v;
    __syncthreads();
    for (int off = THREADS >> 1; off > 0; off >>= 1) {
        if (tid < off) sdata[tid] += sdata[tid + off];
        __syncthreads();
    }
    int r = sdata[0];
    __syncthreads();
    return r;
}

__device__ __forceinline__ int blockScanIncl(int v, int* sdata) {
    int tid = threadIdx.x;
    sdata[tid] = v;
    __syncthreads();
    for (int off = 1; off < THREADS; off <<= 1) {
        int t = 0;
        if (tid >= off) t = sdata[tid - off];
        __syncthreads();
        if (tid >= off) sdata[tid] += t;
        __syncthreads();
    }
    int r = sdata[tid];
    __syncthreads();
    return r;
}

// ---------------------------------------------------------------------------
// One cooperative kernel, 5 phases separated by grid.sync().
//   1: per-chunk count of segment starts
//   2: emit segOff (redundant per-block inter-chunk prefix) + nseg + sentinel
//   3: per-chunk sums of C(c,2)
//   4: emit triOff
//   5: wave-per-segment fill of the T triples (coalesced stores)
// ---------------------------------------------------------------------------
__global__ void k_all(const int* __restrict__ idx, int n, int E, int NB,
                      int* __restrict__ chunkCnt, int* __restrict__ triChunkSum,
                      int* __restrict__ segOff, int* __restrict__ triOff,
                      int* __restrict__ nsegPtr,
                      int* __restrict__ outI, int* __restrict__ outJ,
                      int* __restrict__ outK) {
    cg::grid_group grid = cg::this_grid();
    __shared__ int sdata[THREADS];
    int tid = threadIdx.x, bid = blockIdx.x;

    // ---- phase 1: count segment starts in my E elements -------------------
    int base = (bid * THREADS + tid) * E;
    int cnt = 0;
    for (int j = 0; j < E; ++j) {
        int p = base + j;
        if (p < n) cnt += (p == 0) || (idx[p - 1] != idx[p]);
    }
    int tot = blockReduceSum(cnt, sdata);
    if (tid == 0) chunkCnt[bid] = tot;
    grid.sync();

    // ---- phase 2: emit start positions ------------------------------------
    int pv = 0;
    for (int i = tid; i < bid; i += THREADS) pv += chunkCnt[i];
    int prefix = blockReduceSum(pv, sdata);
    int incl = blockScanIncl(cnt, sdata);        // cnt kept in register
    int off = prefix + incl - cnt;
    for (int j = 0; j < E; ++j) {
        int p = base + j;
        if (p < n && ((p == 0) || (idx[p - 1] != idx[p]))) segOff[off++] = p;
    }
    if (bid == NB - 1 && tid == THREADS - 1) {
        int nseg = prefix + incl;
        *nsegPtr = nseg;
        segOff[nseg] = n;                        // sentinel
    }
    grid.sync();

    // ---- phase 3: per-chunk sums of C(c,2) --------------------------------
    int nseg = *nsegPtr;
    int scnt = 0;
    for (int j = 0; j < E; ++j) {
        int s = base + j;                        // reuse index space
        if (s < nseg) {
            int c = segOff[s + 1] - segOff[s];
            scnt += c * (c - 1) / 2;
        }
    }
    int stot = blockReduceSum(scnt, sdata);
    if (tid == 0) triChunkSum[bid] = stot;
    grid.sync();

    // ---- phase 4: emit triOff ---------------------------------------------
    int pv2 = 0;
    for (int i = tid; i < bid; i += THREADS) pv2 += triChunkSum[i];
    int prefix2 = blockReduceSum(pv2, sdata);
    int incl2 = blockScanIncl(scnt, sdata);
    int run = prefix2 + incl2 - scnt;
    for (int j = 0; j < E; ++j) {
        int s = base + j;
        if (s < nseg) {
            int c = segOff[s + 1] - segOff[s];
            triOff[s] = run;
            run += c * (c - 1) / 2;
        }
    }
    grid.sync();

    // ---- phase 5: fill (wave-per-segment, grid-stride) --------------------
    int wid = bid * (THREADS / 64) + (tid >> 6);
    int lane = tid & 63;
    int nW = NB * (THREADS / 64);
    for (int s = wid; s < nseg; s += nW) {
        int baseP = segOff[s];
        int c = segOff[s + 1] - baseP;
        int M = c * (c - 1) / 2;
        int t0 = triOff[s];
        for (int r = lane; r < M; r += 64) {
            int rr = M - 1 - r;
            int k = (int)floorf((sqrtf((float)(8 * rr + 1)) - 1.0f) * 0.5f);
            if (k < 0) k = 0;
            while ((k + 1) * (k + 2) / 2 <= rr) ++k;   // exact fix-up
            while (k * (k + 1) / 2 > rr) --k;
            int a = c - 2 - k;
            int b = c - 1 - (rr - k * (k + 1) / 2);
            int t = t0 + r;
            outI[t] = s;
            outJ[t] = baseP + a;
            outK[t] = baseP + b;
        }
    }
}

extern "C" void kernel_launch(void* const* d_in, const int* in_sizes, int n_in,
                              void* d_out, int out_size, void* d_ws, size_t ws_size,
                              hipStream_t stream) {
    const int* idx = (const int*)d_in[0];
    int n = in_sizes[0];
    int T = out_size / 3;
    int* out = (int*)d_out;
    int* ws = (int*)d_ws;

    // workspace layout (ints)
    int* nsegPtr     = ws;                    // [1]
    int* chunkCnt    = ws + 16;               // [1024]
    int* triChunkSum = ws + 16 + 1024;        // [1024]
    int* segOff      = ws + 16 + 2048;        // [n+1] (sentinel at nseg)
    int* triOff      = segOff + (n + 1);      // [n]

    // per-thread element count so #chunks <= 1024 (cooperative co-residency ok)
    int E = 8;
    while ((long long)(n + THREADS * E - 1) / (THREADS * E) > 1024) E <<= 1;
    int chunk = THREADS * E;
    int NB = (n + chunk - 1) / chunk;

    int* outI = out;
    int* outJ = out + T;
    int* outK = out + 2 * T;

    void* args[] = {(void*)&idx, (void*)&n, (void*)&E, (void*)&NB,
                    (void*)&chunkCnt, (void*)&triChunkSum,
                    (void*)&segOff, (void*)&triOff, (void*)&nsegPtr,
                    (void*)&outI, (void*)&outJ, (void*)&outK};
    hipLaunchCooperativeKernel((void*)k_all, dim3(NB), dim3(THREADS),
                               args, 0, stream);
}

// Round 4
// 177.059 us; speedup vs baseline: 2.2023x; 2.2023x over previous
//
#include <hip/hip_runtime.h>

#define THREADS 256
#define FILL_BLOCKS 4096

// ---------------------------------------------------------------------------
// Block helpers (each leaves sdata reusable: trailing __syncthreads()).
// ---------------------------------------------------------------------------
__device__ __forceinline__ int blockReduceSum(int v, int* sdata) {
    int tid = threadIdx.x;
    sdata[tid] = v;
    __syncthreads();
    for (int off = THREADS >> 1; off > 0; off >>= 1) {
        if (tid < off) sdata[tid] += sdata[tid + off];
        __syncthreads();
    }
    int r = sdata[0];
    __syncthreads();
    return r;
}

__device__ __forceinline__ int blockScanIncl(int v, int* sdata) {
    int tid = threadIdx.x;
    sdata[tid] = v;
    __syncthreads();
    for (int off = 1; off < THREADS; off <<= 1) {
        int t = 0;
        if (tid >= off) t = sdata[tid - off];
        __syncthreads();
        if (tid >= off) sdata[tid] += t;
        __syncthreads();
    }
    int r = sdata[tid];
    __syncthreads();
    return r;
}

// decode condensed rank: rr = M-1-r, returns local (a,b), b>a
__device__ __forceinline__ void decodeRank(int rr, int c, int& a, int& b) {
    int k = (int)floorf((sqrtf((float)(8 * rr + 1)) - 1.0f) * 0.5f);
    if (k < 0) k = 0;
    while ((k + 1) * (k + 2) / 2 <= rr) ++k;   // exact fix-up
    while (k * (k + 1) / 2 > rr) --k;
    a = c - 2 - k;
    b = c - 1 - (rr - k * (k + 1) / 2);
}

// ---------------------------------------------------------------------------
// Kernel 1: per-chunk count of segment starts AND per-chunk sum of C(c,2).
// Segment length found by forward scan from each start (L1/L2-hot reads).
// ---------------------------------------------------------------------------
__global__ void k_count(const int* __restrict__ idx, int n, int E,
                        int* __restrict__ chunkCnt,
                        int* __restrict__ triChunkSum) {
    __shared__ int sdata[THREADS];
    int base = (blockIdx.x * THREADS + threadIdx.x) * E;
    int cnt = 0, triSum = 0;
    for (int j = 0; j < E; ++j) {
        int p = base + j;
        if (p < n && ((p == 0) || (idx[p - 1] != idx[p]))) {
            ++cnt;
            int v = idx[p];
            int q = p + 1;
            while (q < n && idx[q] == v) ++q;
            int c = q - p;
            triSum += c * (c - 1) / 2;
        }
    }
    int t1 = blockReduceSum(cnt, sdata);
    if (threadIdx.x == 0) chunkCnt[blockIdx.x] = t1;
    int t2 = blockReduceSum(triSum, sdata);
    if (threadIdx.x == 0) triChunkSum[blockIdx.x] = t2;
}

// ---------------------------------------------------------------------------
// Kernel 2: redundant inter-chunk prefix (both arrays), emit segOff + triOff,
// last block writes nseg + segOff[nseg]=n sentinel.
// ---------------------------------------------------------------------------
__global__ void k_emit(const int* __restrict__ idx, int n, int E, int NB,
                       const int* __restrict__ chunkCnt,
                       const int* __restrict__ triChunkSum,
                       int* __restrict__ segOff, int* __restrict__ triOff,
                       int* __restrict__ nsegPtr) {
    __shared__ int sdata[THREADS];
    int tid = threadIdx.x, bid = blockIdx.x;

    int pv = 0, tv = 0;
    for (int i = tid; i < bid; i += THREADS) {
        pv += chunkCnt[i];
        tv += triChunkSum[i];
    }
    int segBase = blockReduceSum(pv, sdata);
    int triBase = blockReduceSum(tv, sdata);

    int base = (bid * THREADS + tid) * E;
    int cnt = 0, triCnt = 0;
    for (int j = 0; j < E; ++j) {
        int p = base + j;
        if (p < n && ((p == 0) || (idx[p - 1] != idx[p]))) {
            ++cnt;
            int v = idx[p];
            int q = p + 1;
            while (q < n && idx[q] == v) ++q;
            int c = q - p;
            triCnt += c * (c - 1) / 2;
        }
    }
    int inclC = blockScanIncl(cnt, sdata);
    int inclT = blockScanIncl(triCnt, sdata);

    int ord  = segBase + inclC - cnt;
    int trun = triBase + inclT - triCnt;
    for (int j = 0; j < E; ++j) {
        int p = base + j;
        if (p < n && ((p == 0) || (idx[p - 1] != idx[p]))) {
            int v = idx[p];
            int q = p + 1;
            while (q < n && idx[q] == v) ++q;
            int c = q - p;
            segOff[ord] = p;
            triOff[ord] = trun;
            ++ord;
            trun += c * (c - 1) / 2;
        }
    }
    if (bid == NB - 1 && tid == THREADS - 1) {
        int nseg = segBase + inclC;
        *nsegPtr = nseg;
        segOff[nseg] = n;                        // sentinel for length lookup
    }
}

// ---------------------------------------------------------------------------
// Kernel 3 (hot): triple-balanced fill. Wave w owns output rows
// [T*w/nW, T*(w+1)/nW): binary-search the starting segment once, then walk.
// Stores are coalesced and each wave writes one contiguous span per stream.
// ---------------------------------------------------------------------------
__global__ void k_fill(const int* __restrict__ segOff,
                       const int* __restrict__ triOff,
                       const int* __restrict__ nsegPtr, int T,
                       int* __restrict__ outI, int* __restrict__ outJ,
                       int* __restrict__ outK) {
    int nseg = *nsegPtr;
    int w = blockIdx.x * (THREADS / 64) + (threadIdx.x >> 6);
    int lane = threadIdx.x & 63;
    int nW = gridDim.x * (THREADS / 64);
    long long tlo = (long long)T * w / nW;
    long long thi = (long long)T * (w + 1) / nW;
    if (tlo >= thi) return;

    // largest s with triOff[s] <= tlo
    int lo = 0, hi = nseg - 1;
    while (lo < hi) {
        int mid = (lo + hi + 1) >> 1;
        if (triOff[mid] <= (int)tlo) lo = mid; else hi = mid - 1;
    }
    int s = lo;
    long long t = tlo;
    while (t < thi && s < nseg) {
        int baseP = segOff[s];
        int c = segOff[s + 1] - baseP;
        int M = c * (c - 1) / 2;
        int t0 = triOff[s];
        int rstart = (int)(t - t0);
        int rend = M;
        { long long cap = thi - t0; if (cap < (long long)rend) rend = (int)cap; }
        for (int r = rstart + lane; r < rend; r += 64) {
            int rr = M - 1 - r;
            int a, b;
            decodeRank(rr, c, a, b);
            int tt = t0 + r;
            outI[tt] = s;
            outJ[tt] = baseP + a;
            outK[tt] = baseP + b;
        }
        t = (long long)t0 + rend;
        ++s;
    }
}

extern "C" void kernel_launch(void* const* d_in, const int* in_sizes, int n_in,
                              void* d_out, int out_size, void* d_ws, size_t ws_size,
                              hipStream_t stream) {
    const int* idx = (const int*)d_in[0];
    int n = in_sizes[0];
    int T = out_size / 3;
    int* out = (int*)d_out;
    int* ws = (int*)d_ws;

    // workspace layout (ints)
    int* nsegPtr     = ws;                    // [1]
    int* chunkCnt    = ws + 16;               // [1024]
    int* triChunkSum = ws + 16 + 1024;        // [1024]
    int* segOff      = ws + 16 + 2048;        // [n+1] (sentinel at nseg)
    int* triOff      = segOff + (n + 1);      // [n]

    // per-thread element count so #chunks <= 1024
    int E = 8;
    while ((long long)(n + THREADS * E - 1) / (THREADS * E) > 1024) E <<= 1;
    int chunk = THREADS * E;
    int NB = (n + chunk - 1) / chunk;

    hipLaunchKernelGGL(k_count, dim3(NB), dim3(THREADS), 0, stream,
                       idx, n, E, chunkCnt, triChunkSum);
    hipLaunchKernelGGL(k_emit, dim3(NB), dim3(THREADS), 0, stream,
                       idx, n, E, NB, chunkCnt, triChunkSum,
                       segOff, triOff, nsegPtr);
    hipLaunchKernelGGL(k_fill, dim3(FILL_BLOCKS), dim3(THREADS), 0, stream,
                       segOff, triOff, nsegPtr, T, out, out + T, out + 2 * T);
}

// Round 5
// 103.812 us; speedup vs baseline: 3.7561x; 1.7056x over previous
//
#include <hip/hip_runtime.h>

#define THREADS 256
#define FILL_BLOCKS 4096
#define TRIOFF_BLOCKS 64

// ---------------------------------------------------------------------------
// Block helpers (each leaves sdata reusable: trailing __syncthreads()).
// ---------------------------------------------------------------------------
__device__ __forceinline__ int blockReduceSum(int v, int* sdata) {
    int tid = threadIdx.x;
    sdata[tid] = v;
    __syncthreads();
    for (int off = THREADS >> 1; off > 0; off >>= 1) {
        if (tid < off) sdata[tid] += sdata[tid + off];
        __syncthreads();
    }
    int r = sdata[0];
    __syncthreads();
    return r;
}

__device__ __forceinline__ int blockScanIncl(int v, int* sdata) {
    int tid = threadIdx.x;
    sdata[tid] = v;
    __syncthreads();
    for (int off = 1; off < THREADS; off <<= 1) {
        int t = 0;
        if (tid >= off) t = sdata[tid - off];
        __syncthreads();
        if (tid >= off) sdata[tid] += t;
        __syncthreads();
    }
    int r = sdata[tid];
    __syncthreads();
    return r;
}

// ---------------------------------------------------------------------------
// Kernel 1: per-chunk count of segment starts (coalesced reads, no walks).
// ---------------------------------------------------------------------------
__global__ void k_count(const int* __restrict__ idx, int n, int E,
                        int* __restrict__ chunkCnt) {
    __shared__ int sdata[THREADS];
    int base = (blockIdx.x * THREADS + threadIdx.x) * E;
    int cnt = 0;
    for (int j = 0; j < E; ++j) {
        int p = base + j;
        if (p < n) cnt += (p == 0) || (idx[p - 1] != idx[p]);
    }
    int tot = blockReduceSum(cnt, sdata);
    if (threadIdx.x == 0) chunkCnt[blockIdx.x] = tot;
}

// ---------------------------------------------------------------------------
// Kernel 2: emit segOff (redundant inter-chunk prefix), nseg, sentinel.
// ---------------------------------------------------------------------------
__global__ void k_emit_starts(const int* __restrict__ idx, int n, int E, int NB,
                              const int* __restrict__ chunkCnt,
                              int* __restrict__ segOff,
                              int* __restrict__ nsegPtr) {
    __shared__ int sdata[THREADS];
    int tid = threadIdx.x, bid = blockIdx.x;

    int pv = 0;
    for (int i = tid; i < bid; i += THREADS) pv += chunkCnt[i];
    int prefix = blockReduceSum(pv, sdata);

    int base = (bid * THREADS + tid) * E;
    int cnt = 0;
    for (int j = 0; j < E; ++j) {
        int p = base + j;
        if (p < n) cnt += (p == 0) || (idx[p - 1] != idx[p]);
    }
    int incl = blockScanIncl(cnt, sdata);
    int off = prefix + incl - cnt;
    for (int j = 0; j < E; ++j) {
        int p = base + j;
        if (p < n && ((p == 0) || (idx[p - 1] != idx[p]))) segOff[off++] = p;
    }
    if (bid == NB - 1 && tid == THREADS - 1) {
        int nseg = prefix + incl;
        *nsegPtr = nseg;
        segOff[nseg] = n;                        // sentinel
    }
}

// ---------------------------------------------------------------------------
// Kernel 3: emit triOff in ONE kernel. Each block redundantly computes the
// full C(c,2) prefix before its segment range (strided coalesced reads of
// segOff, L2-hot), then a block-local scan emits its contiguous range.
// ---------------------------------------------------------------------------
__global__ void k_trioff(const int* __restrict__ segOff,
                         const int* __restrict__ nsegPtr,
                         int* __restrict__ triOff) {
    __shared__ int sdata[THREADS];
    int nseg = *nsegPtr;
    int tid = threadIdx.x, bid = blockIdx.x;
    int chunkSeg = (nseg + gridDim.x - 1) / gridDim.x;
    int s0 = bid * chunkSeg; if (s0 > nseg) s0 = nseg;
    int s1 = s0 + chunkSeg; if (s1 > nseg) s1 = nseg;

    // prefix over [0, s0): strided, coalesced
    int pv = 0;
    for (int s = tid; s < s0; s += THREADS) {
        int c = segOff[s + 1] - segOff[s];
        pv += c * (c - 1) / 2;
    }
    int prefix = blockReduceSum(pv, sdata);

    // per-thread contiguous sub-range of [s0, s1)
    int tE = (chunkSeg + THREADS - 1) / THREADS;
    int a0 = s0 + tid * tE;
    int a1 = a0 + tE; if (a1 > s1) a1 = s1;
    int lsum = 0;
    for (int s = a0; s < a1; ++s) {
        int c = segOff[s + 1] - segOff[s];
        lsum += c * (c - 1) / 2;
    }
    int incl = blockScanIncl(lsum, sdata);
    int run = prefix + incl - lsum;
    for (int s = a0; s < a1; ++s) {
        int c = segOff[s + 1] - segOff[s];
        triOff[s] = run;
        run += c * (c - 1) / 2;
    }
}

// ---------------------------------------------------------------------------
// Kernel 4 (hot): wave-per-segment fill, rank-pair vectorized.
// Decode rank r0, derive r0+1 lexicographically; int2 stores (8 B/lane).
// Head rank 0 = (0,1), tail rank M-1 = (c-2,c-1) are decode-free.
// TEVEN: outJ (= out+T) shares int2 alignment parity iff T is even.
// ---------------------------------------------------------------------------
template <bool TEVEN>
__global__ void k_fill(const int* __restrict__ segOff,
                       const int* __restrict__ triOff,
                       const int* __restrict__ nsegPtr,
                       int* __restrict__ outI, int* __restrict__ outJ,
                       int* __restrict__ outK) {
    int nseg = *nsegPtr;
    int wid = blockIdx.x * (THREADS / 64) + (threadIdx.x >> 6);
    int lane = threadIdx.x & 63;
    int nW = gridDim.x * (THREADS / 64);
    for (int s = wid; s < nseg; s += nW) {
        int baseP = segOff[s];
        int c = segOff[s + 1] - baseP;
        int M = c * (c - 1) / 2;
        if (M <= 0) continue;
        int t0 = triOff[s];
        int h = t0 & 1;                      // align pair stores to even t
        if (h && lane == 0) {                // head: rank 0 = (0,1)
            outI[t0] = s;
            outJ[t0] = baseP;
            outK[t0] = baseP + 1;
        }
        int npairs = (M - h) >> 1;
        for (int pi = lane; pi < npairs; pi += 64) {
            int r0 = h + 2 * pi;
            int rr = M - 1 - r0;
            int k = (int)floorf((sqrtf((float)(8 * rr + 1)) - 1.0f) * 0.5f);
            if (k < 0) k = 0;
            while ((k + 1) * (k + 2) / 2 <= rr) ++k;   // exact fix-up
            while (k * (k + 1) / 2 > rr) --k;
            int a0v = c - 2 - k;
            int b0v = c - 1 - (rr - k * (k + 1) / 2);
            int a1v, b1v;                    // derive rank r0+1
            if (b0v == c - 1) { a1v = a0v + 1; b1v = a0v + 2; }
            else              { a1v = a0v;     b1v = b0v + 1; }
            int t = t0 + r0;                 // even
            *reinterpret_cast<int2*>(outI + t) = make_int2(s, s);
            *reinterpret_cast<int2*>(outK + t) = make_int2(baseP + b0v, baseP + b1v);
            if (TEVEN) {
                *reinterpret_cast<int2*>(outJ + t) = make_int2(baseP + a0v, baseP + a1v);
            } else {
                outJ[t]     = baseP + a0v;
                outJ[t + 1] = baseP + a1v;
            }
        }
        if (((M - h) & 1) && lane == 0) {    // tail: rank M-1 = (c-2,c-1)
            int t = t0 + M - 1;
            outI[t] = s;
            outJ[t] = baseP + c - 2;
            outK[t] = baseP + c - 1;
        }
    }
}

extern "C" void kernel_launch(void* const* d_in, const int* in_sizes, int n_in,
                              void* d_out, int out_size, void* d_ws, size_t ws_size,
                              hipStream_t stream) {
    const int* idx = (const int*)d_in[0];
    int n = in_sizes[0];
    int T = out_size / 3;
    int* out = (int*)d_out;
    int* ws = (int*)d_ws;

    // workspace layout (ints) — identical footprint to round 2
    int* nsegPtr  = ws;                      // [1]
    int* chunkCnt = ws + 16;                 // [1024]
    int* segOff   = ws + 16 + 2048;          // [n+1] (sentinel at nseg)
    int* triOff   = segOff + (n + 1);        // [n]

    // per-thread element count so #chunks <= 1024
    int E = 8;
    while ((long long)(n + THREADS * E - 1) / (THREADS * E) > 1024) E <<= 1;
    int chunk = THREADS * E;
    int NB = (n + chunk - 1) / chunk;

    hipLaunchKernelGGL(k_count, dim3(NB), dim3(THREADS), 0, stream,
                       idx, n, E, chunkCnt);
    hipLaunchKernelGGL(k_emit_starts, dim3(NB), dim3(THREADS), 0, stream,
                       idx, n, E, NB, chunkCnt, segOff, nsegPtr);
    hipLaunchKernelGGL(k_trioff, dim3(TRIOFF_BLOCKS), dim3(THREADS), 0, stream,
                       segOff, nsegPtr, triOff);
    if ((T & 1) == 0) {
        hipLaunchKernelGGL((k_fill<true>), dim3(FILL_BLOCKS), dim3(THREADS), 0,
                           stream, segOff, triOff, nsegPtr,
                           out, out + T, out + 2 * T);
    } else {
        hipLaunchKernelGGL((k_fill<false>), dim3(FILL_BLOCKS), dim3(THREADS), 0,
                           stream, segOff, triOff, nsegPtr,
                           out, out + T, out + 2 * T);
    }
}